// Round 1
// 804.410 us; speedup vs baseline: 1.0846x; 1.0846x over previous
//
#include <hip/hip_runtime.h>

// Shapes: B=256, P=196, ENC=2048, WORD=512, ATT=512
#define B_   256
#define P_   196
#define E_   2048
#define WD_  512
#define A_   512
#define M_   (B_ * P_)   // 50176 = 784 * 64

typedef __bf16 bf16x8 __attribute__((ext_vector_type(8)));
typedef float  f32x4  __attribute__((ext_vector_type(4)));

using u16 = unsigned short;
using u32 = unsigned int;

__device__ inline u16 f2bf(float f) {  // RNE
    u32 u; __builtin_memcpy(&u, &f, 4);
    u += 0x7FFFu + ((u >> 16) & 1u); return (u16)(u >> 16);
}

// async global->LDS, 16B per lane, dest = wave-uniform base + lane*16
__device__ inline void gld_lds16(const void* g, void* l) {
    __builtin_amdgcn_global_load_lds(
        (const __attribute__((address_space(1))) u32*)g,
        (__attribute__((address_space(3))) u32*)l, 16, 0, 0);
}

// ---------------------------------------------------------------------------
// k_prep: W_enc fp32 [E][A] -> Wt bf16 [A][E] (transpose + convert).
// ---------------------------------------------------------------------------
__global__ __launch_bounds__(256) void k_prep(const float* __restrict__ We,
                                              u16* __restrict__ Wt) {
    __shared__ float tile[32][33];
    const int tx = threadIdx.x & 31, ty = threadIdx.x >> 5;
    const int k0 = blockIdx.x * 32, n0 = blockIdx.y * 32;
#pragma unroll
    for (int i = 0; i < 4; ++i)
        tile[ty + i * 8][tx] = We[(size_t)(k0 + ty + i * 8) * A_ + n0 + tx];
    __syncthreads();
#pragma unroll
    for (int i = 0; i < 4; ++i)
        Wt[(size_t)(n0 + ty + i * 8) * E_ + k0 + tx] = f2bf(tile[tx][ty + i * 8]);
}

// ---------------------------------------------------------------------------
// k_att_dec: att_dec[b][a] = dot(dec[b,:], Wd[:,a]) + bd[a]
// ---------------------------------------------------------------------------
__global__ __launch_bounds__(512) void k_att_dec(const float* __restrict__ dec,
                                                 const float* __restrict__ Wd,
                                                 const float* __restrict__ bd,
                                                 float* __restrict__ att_dec) {
    int b = blockIdx.x, a = threadIdx.x;
    __shared__ float sd[WD_];
    sd[a] = dec[b * WD_ + a];
    __syncthreads();
    float acc = bd[a];
#pragma unroll 8
    for (int e = 0; e < WD_; ++e)
        acc = fmaf(sd[e], Wd[e * A_ + a], acc);
    att_dec[b * A_ + a] = acc;
}

// ---------------------------------------------------------------------------
// k_logits v3: att[m] = sum_n relu(enc[m,:].W_enc[:,n] + be[n] + att_dec[b][n]) * Wf[n]
//
// Block 512 = 8 waves, M-tile 64 x N=512, BK=32, mfma_f32_16x16x32_bf16.
// Wave w owns cols [w*64, w*64+64) -> acc[4 rt][4 ct].
//
// v3 structural change (T3 2-phase recipe): per K-step,
//   (1) ISSUE next tile's staging first:
//       * B: 4x global_load_lds dwordx4 per wave into its own LDS slice,
//         XOR slot-swizzle (slot ^= (n>>1)&3 on 16B slots within each 64B
//         row) applied on the GLOBAL source so ds_read_b128 frag reads are
//         canonical 2-way (= conflict-free); linear LDS dest (rule #21).
//       * A: reg prefetch depth 2 + fp32->bf16 cvt + fragment-order LDS
//         write (unchanged from v2; measured 0 bank conflicts).
//   (2) ds_read frags from current buffer, 16 MFMA per wave,
//   (3) one __syncthreads. The barrier's vmcnt(0) drain now lands AFTER
//       ~1.2k cycles of MFMA covered the load latency, instead of draining
//       loads issued moments earlier (the v2 stall).
// LDS: sB 2x32KB + sA 2x4KB + sred 2KB = 74KB -> 2 blocks/CU.
// ---------------------------------------------------------------------------
__global__ __launch_bounds__(512, 4) void k_logits(
        const float* __restrict__ enc, const u16* __restrict__ Wt,
        const float* __restrict__ be, const float* __restrict__ Wf,
        const float* __restrict__ att_dec, float* __restrict__ att) {
    __shared__ u16    sB[2][A_ * 32];   // [buf][n*32 + slot*8 + e], swizzled
    __shared__ bf16x8 sA[2][256];       // frag order: [rt*64 + lane]
    __shared__ float  sred[8][64];

    const int t   = threadIdx.x;
    const int w   = t >> 6;             // wave 0..7
    const int L   = t & 63;
    const int l15 = L & 15;
    const int q   = L >> 4;             // 0..3
    const int m0  = blockIdx.x * 64;

    const f32x4 zero = {0.f, 0.f, 0.f, 0.f};
    f32x4 acc[4][4];
#pragma unroll
    for (int rt = 0; rt < 4; ++rt)
#pragma unroll
        for (int ct = 0; ct < 4; ++ct) acc[rt][ct] = zero;

    // --- A staging mapping (unchanged): thread t stages half-slot s=t>>1, h=t&1.
    const int s    = t >> 1, h = t & 1;
    const int srt  = s >> 6;
    const int sL   = s & 63;
    const float* ap = enc + (size_t)(m0 + srt * 16 + (sL & 15)) * E_
                          + (sL >> 4) * 8 + h * 4;
    u32* slds  = (u32*)&sA[0][s] + h * 2;
    u32* slds1 = (u32*)&sA[1][s] + h * 2;

    // --- B staging: wave w stages its own 64 n-rows. Per inst j (16 rows):
    //   lane L -> row n = w*64 + j*16 + (L>>2), LDS slot (L&3),
    //   global k-slot = (L&3) ^ ((n>>1)&3) = (L&3) ^ ((L>>3)&3).
    const int brow  = L >> 2;
    const int bslot = (L & 3) ^ ((L >> 3) & 3);
    const u16* bsrc = Wt + (size_t)(w * 64 + brow) * E_ + bslot * 8;
    u16* bdst0 = &sB[0][(w * 64) * 32];
    u16* bdst1 = &sB[1][(w * 64) * 32];

    // --- B frag-read offsets (swizzled): n = w*64+ct*16+l15, slot = q^((l15>>1)&3)
    int bro[4];
#pragma unroll
    for (int ct = 0; ct < 4; ++ct) {
        int n = w * 64 + ct * 16 + l15;
        int slot = q ^ ((l15 >> 1) & 3);
        bro[ct] = n * 32 + slot * 8;
    }

    // --- prologue: B(0)->buf0 (async), A(0)->buf0 (reg+cvt), aN1=A(1) ---
#pragma unroll
    for (int j = 0; j < 4; ++j)
        gld_lds16(bsrc + (size_t)j * 16 * E_, bdst0 + j * 512);
    float4 aN1 = *(const float4*)(ap);                   // A(0)
    float4 aN2 = *(const float4*)(ap + 32);              // A(1)
    {
        u32 lo = (u32)f2bf(aN1.x) | ((u32)f2bf(aN1.y) << 16);
        u32 hi = (u32)f2bf(aN1.z) | ((u32)f2bf(aN1.w) << 16);
        slds[0] = lo; slds[1] = hi;
    }
    aN1 = aN2;                                           // now A(1)
    __syncthreads();

    for (int kt = 0; kt < 64; ++kt) {
        const int buf = kt & 1;

        // (1) issue next-tile staging FIRST (latency hides under MFMA)
        if (kt < 63) {
            const u16* bs = bsrc + (size_t)(kt + 1) * 32;
            u16* bd = buf ? bdst0 : bdst1;
#pragma unroll
            for (int j = 0; j < 4; ++j)
                gld_lds16(bs + (size_t)j * 16 * E_, bd + j * 512);
        }
        const int kA = (kt + 2 < 64) ? kt + 2 : 63;
        aN2 = *(const float4*)(ap + (size_t)kA * 32);

        // (2) frag reads + MFMA on current buffer
        bf16x8 af[4];
#pragma unroll
        for (int rt = 0; rt < 4; ++rt) af[rt] = sA[buf][rt * 64 + L];
        const u16* sbb = sB[buf];
        bf16x8 bv[4];
#pragma unroll
        for (int ct = 0; ct < 4; ++ct)
            __builtin_memcpy(&bv[ct], sbb + bro[ct], 16);

#pragma unroll
        for (int ct = 0; ct < 4; ++ct) {
#pragma unroll
            for (int rt = 0; rt < 4; ++rt)
                acc[rt][ct] = __builtin_amdgcn_mfma_f32_16x16x32_bf16(
                    af[rt], bv[ct], acc[rt][ct], 0, 0, 0);
        }

        // write A(kt+1) -> other buffer (aN1 issued >= 1 iter ago)
        {
            u32 lo = (u32)f2bf(aN1.x) | ((u32)f2bf(aN1.y) << 16);
            u32 hi = (u32)f2bf(aN1.z) | ((u32)f2bf(aN1.w) << 16);
            u32* d = buf ? slds : slds1;
            d[0] = lo; d[1] = hi;
        }
        aN1 = aN2;

        // (3) single barrier per K-step
        __syncthreads();
    }

    // --- epilogue: relu(acc + be + att_dec) . Wf, reduce over n (unchanged) ---
    float wf[4], bev[4];
#pragma unroll
    for (int ct = 0; ct < 4; ++ct) {
        int n = w * 64 + ct * 16 + l15;
        wf[ct]  = Wf[n];
        bev[ct] = be[n];
    }
#pragma unroll
    for (int rt = 0; rt < 4; ++rt) {
#pragma unroll
        for (int reg = 0; reg < 4; ++reg) {
            int ml = rt * 16 + q * 4 + reg;              // C/D: row = q*4+reg
            int b  = (m0 + ml) / P_;
            const float* adp = att_dec + (size_t)b * A_ + w * 64 + l15;
            float p = 0.f;
#pragma unroll
            for (int ct = 0; ct < 4; ++ct) {
                float hx = acc[rt][ct][reg] + bev[ct] + adp[ct * 16];
                p = fmaf(fmaxf(hx, 0.f), wf[ct], p);
            }
#pragma unroll
            for (int off = 8; off > 0; off >>= 1)
                p += __shfl_down(p, off, 16);
            if (l15 == 0) sred[w][ml] = p;
        }
    }
    __syncthreads();
    if (t < 64) {
        float r = 0.f;
#pragma unroll
        for (int ww = 0; ww < 8; ++ww) r += sred[ww][t];
        att[m0 + t] = r;
    }
}

// ---------------------------------------------------------------------------
// k_out v2: softmax over P then weighted feature sum. (unchanged)
// ---------------------------------------------------------------------------
__global__ __launch_bounds__(256) void k_out(const float* __restrict__ enc,
                                             const float* __restrict__ att,
                                             float* __restrict__ out) {
    int b = blockIdx.x, t = threadIdx.x;
    __shared__ float sw[P_];
    __shared__ float red[8];
    __shared__ f32x4 spart[4][64];

    float v = (t < P_) ? att[b * P_ + t] : -1e30f;
    float m = v;
#pragma unroll
    for (int off = 32; off > 0; off >>= 1)
        m = fmaxf(m, __shfl_down(m, off, 64));
    int wid = t >> 6;
    if ((t & 63) == 0) red[wid] = m;
    __syncthreads();
    m = fmaxf(fmaxf(red[0], red[1]), fmaxf(red[2], red[3]));

    float ev = (t < P_) ? __expf(v - m) : 0.f;
    float ssum = ev;
#pragma unroll
    for (int off = 32; off > 0; off >>= 1)
        ssum += __shfl_down(ssum, off, 64);
    if ((t & 63) == 0) red[4 + wid] = ssum;
    __syncthreads();
    ssum = red[4] + red[5] + red[6] + red[7];
    if (t < P_) sw[t] = ev / ssum;
    __syncthreads();

    const int tq = t >> 6, lane = t & 63;
    const int e0 = blockIdx.y * 256 + lane * 4;
    const float* ep = enc + (size_t)b * P_ * E_ + e0;
    f32x4 acc = {0.f, 0.f, 0.f, 0.f};
    const int p0 = tq * 49;                               // 196 = 4*49
#pragma unroll 7
    for (int i = 0; i < 49; ++i) {
        int p = p0 + i;
        float4 qv = *(const float4*)(ep + (size_t)p * E_);
        float wgt = sw[p];
        acc[0] = fmaf(wgt, qv.x, acc[0]);
        acc[1] = fmaf(wgt, qv.y, acc[1]);
        acc[2] = fmaf(wgt, qv.z, acc[2]);
        acc[3] = fmaf(wgt, qv.w, acc[3]);
    }
    spart[tq][lane] = acc;
    __syncthreads();
    if (tq == 0) {
        f32x4 r = spart[0][lane];
#pragma unroll
        for (int g = 1; g < 4; ++g) {
            f32x4 x = spart[g][lane];
            r[0] += x[0]; r[1] += x[1]; r[2] += x[2]; r[3] += x[3];
        }
        float* op = out + (size_t)b * E_ + e0;
        op[0] = r[0]; op[1] = r[1]; op[2] = r[2]; op[3] = r[3];
    }
}

// ---------------------------------------------------------------------------
extern "C" void kernel_launch(void* const* d_in, const int* in_sizes, int n_in,
                              void* d_out, int out_size, void* d_ws, size_t ws_size,
                              hipStream_t stream) {
    const float* enc   = (const float*)d_in[0];  // [B,P,E]
    const float* dec   = (const float*)d_in[1];  // [B,WD]
    const float* W_enc = (const float*)d_in[2];  // [E,A]
    const float* b_enc = (const float*)d_in[3];  // [A]
    const float* W_dec = (const float*)d_in[4];  // [WD,A]
    const float* b_dec = (const float*)d_in[5];  // [A]
    const float* W_fin = (const float*)d_in[6];  // [A]
    // d_in[7] = b_fin: softmax-invariant -> unused.

    float* att_dec = (float*)d_ws;               // 256*512 f32
    float* att     = att_dec + B_ * A_;          // 50176 f32
    u16*   Wt      = (u16*)(att + M_);           // 512*2048 bf16

    k_prep<<<dim3(E_ / 32, A_ / 32), 256, 0, stream>>>(W_enc, Wt);
    k_att_dec<<<B_, 512, 0, stream>>>(dec, W_dec, b_dec, att_dec);
    k_logits<<<M_ / 64, 512, 0, stream>>>(enc, Wt, b_enc, W_fin, att_dec, att);
    k_out<<<dim3(B_, 8), 256, 0, stream>>>(enc, att, (float*)d_out);
}